// Round 7
// baseline (244.616 us; speedup 1.0000x reference)
//
#include <hip/hip_runtime.h>
#include <hip/hip_bf16.h>
#include <cstdint>

// LSTM cell: g[g,b,n] = sum_k A[b,k] * Wcat[g,k,n],  A = [x | h]  (K = 2048)
// i,f,o = sigmoid(g0,1,2), u = tanh(g3), c_t = i*u + f*c, h_t = o*tanh(c_t)
// Round 7: big-register-tile GEMM. Wave tile 128 x 128eff (acc 256 regs ->
// AGPRs), 1 wave/SIMD, NO intra-step barriers/asm — overlap comes from the
// 128-deep independent MFMA issue window hiding ds_read + staging latency.
// Per-CU LDS traffic halves vs r5 (F/B 42.7 -> 64). nt-slab-per-XCD grid
// mapping keeps each XCD's W-slab (2MB) L2-resident.

#define LDS_TOTAL 131072    // 2 buf x (A[256][64] 32KB + B[4][64][64] 32KB)

typedef __attribute__((ext_vector_type(8))) short bf16x8;   // 8 bf16 = 4 VGPR
typedef __attribute__((ext_vector_type(4))) float f32x4;
typedef __attribute__((ext_vector_type(4))) unsigned int u32x4;

static __device__ __forceinline__ unsigned short f2bf(float f) {
  union { float f; unsigned int u; } v; v.f = f;
  unsigned int u = v.u;
  unsigned int r = (u + 0x7FFFu + ((u >> 16) & 1u)) >> 16;  // RTN-even
  return (unsigned short)r;
}

static __device__ __forceinline__ void load16(const void* gp, void* lp) {
  __builtin_amdgcn_global_load_lds(
      (const __attribute__((address_space(1))) void*)gp,
      (__attribute__((address_space(3))) void*)lp, 16, 0, 0);
}

static __device__ __forceinline__ float sigmoid_f(float x) {
  return 1.0f / (1.0f + __expf(-x));
}
static __device__ __forceinline__ float tanh_f(float x) {
  float e = __expf(-2.0f * fabsf(x));
  float r = (1.0f - e) / (1.0f + e);
  return copysignf(r, x);
}

// ---- prep 1: pack A = [x | h] as bf16 [8192][2048] ----
__global__ __launch_bounds__(256) void pack_a_kernel(
    const float* __restrict__ x, const float* __restrict__ h,
    unsigned short* __restrict__ Apack) {
  int t = blockIdx.x * 256 + threadIdx.x;
  size_t base = (size_t)t * 8;
  int b = (int)(base >> 11);
  int k = (int)(base & 2047);
  const float* src = (k < 1024) ? (x + (size_t)b * 1024 + k)
                                : (h + (size_t)b * 1024 + (k - 1024));
  float4 v0 = ((const float4*)src)[0];
  float4 v1 = ((const float4*)src)[1];
  union { unsigned short s[8]; u32x4 v; } o;
  o.s[0] = f2bf(v0.x); o.s[1] = f2bf(v0.y); o.s[2] = f2bf(v0.z); o.s[3] = f2bf(v0.w);
  o.s[4] = f2bf(v1.x); o.s[5] = f2bf(v1.y); o.s[6] = f2bf(v1.z); o.s[7] = f2bf(v1.w);
  *(u32x4*)(Apack + base) = o.v;
}

// ---- prep 2: Wt[g][n][k] = bf16( k<1024 ? Wx[g][k][n] : Wh[g][k-1024][n] ) ----
__global__ __launch_bounds__(256) void prep_w_kernel(
    const float* __restrict__ Wx, const float* __restrict__ Wh,
    unsigned short* __restrict__ Wt) {
  __shared__ float tile[32][33];
  int bid = blockIdx.x;
  int g = bid >> 11;
  int rem = bid & 2047;
  int kt = rem >> 5;
  int nt = rem & 31;
  int k0 = kt * 32, n0 = nt * 32;
  int tx = threadIdx.x & 31, ty = threadIdx.x >> 5;
  const float* Wsrc;
  int ks;
  if (k0 < 1024) { Wsrc = Wx + (size_t)g * 1048576; ks = k0; }
  else           { Wsrc = Wh + (size_t)g * 1048576; ks = k0 - 1024; }
  #pragma unroll
  for (int s = 0; s < 4; ++s) {
    int r = ty + s * 8;
    tile[r][tx] = Wsrc[(size_t)(ks + r) * 1024 + n0 + tx];
  }
  __syncthreads();
  #pragma unroll
  for (int s = 0; s < 4; ++s) {
    int r = ty + s * 8;
    Wt[(size_t)((g << 10) + n0 + r) * 2048 + k0 + tx] = f2bf(tile[tx][r]);
  }
}

// ---- main: fused 4-gate GEMM + LSTM epilogue, big register tile ----
// 256 thr = 4 waves (wr = w>>1: rows wr*128..+128; wc = w&1: n wc*32..+32 per
// gate). Block tile 256 rows x (4g x 64n). acc[8][4][2] f32x4 = 256 regs.
// Buf (64KB): A[256][64] @0, B[4][64][64] @32768. One __syncthreads per
// K-step; stage(t+1) issued first, lands during the 128-MFMA window.
__global__ __launch_bounds__(256, 1) void lstm_gemm_kernel(
    const unsigned short* __restrict__ Apack,   // [8192][2048] bf16
    const unsigned short* __restrict__ Wt,      // [4][1024][2048] bf16 (B^T)
    const float* __restrict__ cprev,
    float* __restrict__ out) {
  extern __shared__ char lds[];
  const int tid = threadIdx.x;
  const int l = tid & 63;
  const int w = tid >> 6;              // 0..3
  const int wr = w >> 1;               // 0..1
  const int wc = w & 1;                // 0..1
  // nt-slab per XCD: dispatch round-robins XCDs by bid [m09]. XCD k gets
  // nt in {2k, 2k+1} -> its W-slab = 2 x 1MB, L2-resident.
  const int bid0 = blockIdx.x;         // 512 blocks
  const int xcd = bid0 & 7;
  const int cc = bid0 >> 3;            // 0..63
  const int nt = xcd * 2 + (cc >> 5);  // 16 n-tiles
  const int mt = cc & 31;              // 32 m-tiles
  const int m0 = mt << 8;              // 256 rows / tile
  const int n0 = nt << 6;              // 64 n / gate / tile

  char* const buf0 = lds;
  char* const buf1 = lds + 65536;

  f32x4 acc[8][4][2];                  // [m-frag][gate][n-frag]
  #pragma unroll
  for (int mf = 0; mf < 8; ++mf)
    #pragma unroll
    for (int g = 0; g < 4; ++g)
      #pragma unroll
      for (int nf = 0; nf < 2; ++nf) acc[mf][g][nf] = (f32x4)0.0f;

  const int lr = l & 15;
  const int kgrp = (l >> 4) << 4;      // 0/16/32/48 byte k-group
  const int sx = (lr & 7) << 4;        // XOR swizzle (row&7 == lr&7 everywhere)
  const int kx0 = kgrp ^ sx;
  const int kx1 = (64 + kgrp) ^ sx;
  const int aoff = (wr * 128 + lr) * 128;
  const int boff = 32768 + (wc * 32 + lr) * 128;

  // Hoisted stage bases (scheme verified r5/r6): chunk = p*256+tid,
  // row = p*32 + tid/8, (row&7) = (tid>>3)&7 -> kb depends only on tid.
  const int arl = tid >> 3;                          // 0..31
  const int akb = ((tid << 4) & 127) ^ ((arl & 7) << 4);
  const unsigned short* const gAbase =
      Apack + (size_t)(m0 + arl) * 2048 + (akb >> 1);
  const unsigned short* const gBbase =
      Wt + (size_t)(n0 + arl) * 2048 + (akb >> 1);
  const int dbase = (tid & ~63) << 4;                // wave-uniform + lane*16

  auto stageAB = [&](char* bufb, int t) {            // 16 gloads/thread
    const unsigned short* ga = gAbase + (t << 6);
    #pragma unroll
    for (int p = 0; p < 8; ++p)                      // A rows p*32..+32
      load16(ga + (size_t)p * 65536, bufb + p * 4096 + dbase);
    const unsigned short* gb = gBbase + (t << 6);
    #pragma unroll
    for (int p = 0; p < 8; ++p)                      // gate p>>1, rows (p&1)*32
      load16(gb + (size_t)(p >> 1) * 2097152 + (size_t)(p & 1) * 65536,
             bufb + 32768 + p * 4096 + dbase);
  };

  bf16x8 aR0[8], aR1[8];               // A frags, kk=0/1
  bf16x8 bR0[4][2], bR1[4][2];         // B frags [gate][nf], kk=0/1

  auto readAll = [&](const char* bufc) {             // 32 ds_read_b128
    #pragma unroll
    for (int mf = 0; mf < 8; ++mf) {
      const char* p = bufc + aoff + mf * 2048;       // +16 rows = 2048B
      aR0[mf] = *(const bf16x8*)(p + kx0);
      aR1[mf] = *(const bf16x8*)(p + kx1);
    }
    #pragma unroll
    for (int g = 0; g < 4; ++g)
      #pragma unroll
      for (int nf = 0; nf < 2; ++nf) {
        const char* p = bufc + boff + g * 8192 + nf * 2048;
        bR0[g][nf] = *(const bf16x8*)(p + kx0);
        bR1[g][nf] = *(const bf16x8*)(p + kx1);
      }
  };

  auto mfmaAll = [&]() {                             // 128 independent MFMAs
    #pragma unroll
    for (int mf = 0; mf < 8; ++mf)
      #pragma unroll
      for (int g = 0; g < 4; ++g)
        #pragma unroll
        for (int nf = 0; nf < 2; ++nf)
          acc[mf][g][nf] = __builtin_amdgcn_mfma_f32_16x16x32_bf16(
              aR0[mf], bR0[g][nf], acc[mf][g][nf], 0, 0, 0);
    #pragma unroll
    for (int mf = 0; mf < 8; ++mf)
      #pragma unroll
      for (int g = 0; g < 4; ++g)
        #pragma unroll
        for (int nf = 0; nf < 2; ++nf)
          acc[mf][g][nf] = __builtin_amdgcn_mfma_f32_16x16x32_bf16(
              aR1[mf], bR1[g][nf], acc[mf][g][nf], 0, 0, 0);
  };

  stageAB(buf0, 0);
  __syncthreads();                     // t=0 staged

  #pragma unroll 1
  for (int t = 0; t < 32; ++t) {
    char* bufc = (t & 1) ? buf1 : buf0;
    char* bufn = (t & 1) ? buf0 : buf1;
    if (t + 1 < 32) stageAB(bufn, t + 1);  // issued ~2500 cyc before consumed
    readAll(bufc);
    mfmaAll();
    __syncthreads();                   // drains vmcnt (loads long landed)
  }

  // Epilogue: C/D layout col = lane&15, row = (lane>>4)*4 + reg  [m89]
  const int q = (l >> 4) << 2;
  #pragma unroll
  for (int mf = 0; mf < 8; ++mf) {
    #pragma unroll
    for (int nf = 0; nf < 2; ++nf) {
      const int col = n0 + wc * 32 + nf * 16 + lr;
      #pragma unroll
      for (int j = 0; j < 4; ++j) {
        int row = m0 + wr * 128 + mf * 16 + q + j;
        float gi = acc[mf][0][nf][j];
        float gf = acc[mf][1][nf][j];
        float go = acc[mf][2][nf][j];
        float gu = acc[mf][3][nf][j];
        float i_ = sigmoid_f(gi);
        float f_ = sigmoid_f(gf);
        float o_ = sigmoid_f(go);
        float u_ = tanh_f(gu);
        size_t idx = (size_t)row * 1024 + col;
        float ct = i_ * u_ + f_ * cprev[idx];
        float ht = o_ * tanh_f(ct);
        out[idx] = ht;                 // h_t
        out[8388608 + idx] = ct;       // c_t
      }
    }
  }
}

extern "C" void kernel_launch(void* const* d_in, const int* in_sizes, int n_in,
                              void* d_out, int out_size, void* d_ws, size_t ws_size,
                              hipStream_t stream) {
  const float* x  = (const float*)d_in[0];
  const float* h  = (const float*)d_in[1];
  const float* c  = (const float*)d_in[2];
  const float* Wx = (const float*)d_in[3];
  const float* Wh = (const float*)d_in[4];
  float* out = (float*)d_out;

  unsigned short* Apack = (unsigned short*)d_ws;                  // 33,554,432 B
  unsigned short* Wt = (unsigned short*)((char*)d_ws + 33554432); // 16,777,216 B

  hipFuncSetAttribute((const void*)lstm_gemm_kernel,
                      hipFuncAttributeMaxDynamicSharedMemorySize, LDS_TOTAL);

  pack_a_kernel<<<8192, 256, 0, stream>>>(x, h, Apack);
  prep_w_kernel<<<8192, 256, 0, stream>>>(Wx, Wh, Wt);
  lstm_gemm_kernel<<<dim3(512), dim3(256), LDS_TOTAL, stream>>>(Apack, Wt, c, out);
}

// Round 8
// 168.529 us; speedup vs baseline: 1.4515x; 1.4515x over previous
//
#include <hip/hip_runtime.h>
#include <hip/hip_bf16.h>
#include <cstdint>

// LSTM cell: g[g,b,n] = sum_k A[b,k] * Wcat[g,k,n],  A = [x | h]  (K = 2048)
// i,f,o = sigmoid(g0,1,2), u = tanh(g3), c_t = i*u + f*c, h_t = o*tanh(c_t)
// Round 8: 32x32x16 MFMA (2495 TF ceiling vs 2176 for 16x16x32, m119) +
// k-chunked operand layouts: LDS A[ksub][half][row][16B], B[ksub][g][half][n]
// -> all ds_reads contiguous-512B conflict-free with base+imm-offset
// addressing; all global_load_lds 1KB-coalesced. Uniform counted vmcnt(12)
// (AITER's steady-state style), tail peeled.

#define LDS_TOTAL 131072    // 2 buf x (A 32KB + B 32KB)

typedef __attribute__((ext_vector_type(8))) short bf16x8;    // 8 bf16 = 4 VGPR
typedef __attribute__((ext_vector_type(16))) float f32x16;   // 32x32 acc
typedef __attribute__((ext_vector_type(4))) unsigned int u32x4;

static __device__ __forceinline__ unsigned short f2bf(float f) {
  union { float f; unsigned int u; } v; v.f = f;
  unsigned int u = v.u;
  unsigned int r = (u + 0x7FFFu + ((u >> 16) & 1u)) >> 16;  // RTN-even
  return (unsigned short)r;
}

static __device__ __forceinline__ void load16(const void* gp, void* lp) {
  __builtin_amdgcn_global_load_lds(
      (const __attribute__((address_space(1))) void*)gp,
      (__attribute__((address_space(3))) void*)lp, 16, 0, 0);
}

static __device__ __forceinline__ float sigmoid_f(float x) {
  return 1.0f / (1.0f + __expf(-x));
}
static __device__ __forceinline__ float tanh_f(float x) {
  float e = __expf(-2.0f * fabsf(x));
  float r = (1.0f - e) / (1.0f + e);
  return copysignf(r, x);
}

// ---- prep 1: A = [x|h] -> k-chunked bf16: Ap[kblk 256][b 8192][8 elems] ----
// 64x64 tile via LDS transpose; reads and writes both coalesced.
__global__ __launch_bounds__(256) void pack_a_kernel(
    const float* __restrict__ x, const float* __restrict__ h,
    unsigned short* __restrict__ Ap) {
  __shared__ float tile[64][65];               // [b][k], pad -> no conflicts
  const int b0 = (blockIdx.x >> 5) << 6;       // 128 b-tiles
  const int k0 = (blockIdx.x & 31) << 6;       // 32 k-tiles
  const float* src; int ks;
  if (k0 < 1024) { src = x; ks = k0; } else { src = h; ks = k0 - 1024; }
  const int r = threadIdx.x >> 4;
  const int c4 = (threadIdx.x & 15) << 2;
  #pragma unroll
  for (int s = 0; s < 4; ++s) {
    float4 v = *(const float4*)(src + (size_t)(b0 + s * 16 + r) * 1024 + ks + c4);
    tile[s * 16 + r][c4 + 0] = v.x; tile[s * 16 + r][c4 + 1] = v.y;
    tile[s * 16 + r][c4 + 2] = v.z; tile[s * 16 + r][c4 + 3] = v.w;
  }
  __syncthreads();
  #pragma unroll
  for (int i = 0; i < 2; ++i) {
    int cc = i * 256 + threadIdx.x;
    int kb = cc >> 6, bb = cc & 63;
    union { unsigned short s[8]; u32x4 v; } o;
    #pragma unroll
    for (int e = 0; e < 8; ++e) o.s[e] = f2bf(tile[bb][kb * 8 + e]);
    *(u32x4*)(Ap + ((size_t)((k0 >> 3) + kb) * 8192 + b0 + bb) * 8) = o.v;
  }
}

// ---- prep 2: W -> k-chunked bf16: Wt2[kblk 256][g 4][n 1024][8 elems] ----
__global__ __launch_bounds__(256) void prep_w_kernel(
    const float* __restrict__ Wx, const float* __restrict__ Wh,
    unsigned short* __restrict__ Wt2) {
  __shared__ float tile[64][65];               // [k][n]
  const int g = blockIdx.x >> 9;               // 4 gates
  const int kt = (blockIdx.x >> 4) & 31;       // 32 k-tiles
  const int nt = blockIdx.x & 15;              // 16 n-tiles
  const int k0 = kt << 6, n0 = nt << 6;
  const float* W; int ks;
  if (k0 < 1024) { W = Wx + (size_t)g * 1048576; ks = k0; }
  else           { W = Wh + (size_t)g * 1048576; ks = k0 - 1024; }
  const int r = threadIdx.x >> 4;
  const int c4 = (threadIdx.x & 15) << 2;
  #pragma unroll
  for (int s = 0; s < 4; ++s) {
    float4 v = *(const float4*)(W + (size_t)(ks + s * 16 + r) * 1024 + n0 + c4);
    tile[s * 16 + r][c4 + 0] = v.x; tile[s * 16 + r][c4 + 1] = v.y;
    tile[s * 16 + r][c4 + 2] = v.z; tile[s * 16 + r][c4 + 3] = v.w;
  }
  __syncthreads();
  #pragma unroll
  for (int i = 0; i < 2; ++i) {
    int cc = i * 256 + threadIdx.x;
    int kb = cc >> 6, nn = cc & 63;
    union { unsigned short s[8]; u32x4 v; } o;
    #pragma unroll
    for (int e = 0; e < 8; ++e) o.s[e] = f2bf(tile[kb * 8 + e][nn]);  // 65-stride col
    *(u32x4*)(Wt2 + ((size_t)((k0 >> 3) + kb) * 4096 + g * 1024 + n0 + nn) * 8) = o.v;
  }
}

#define VMW(n) asm volatile("s_waitcnt vmcnt(" #n ")" ::: "memory")

// ---- main: fused 4-gate GEMM (32x32x16 MFMA) + LSTM epilogue ----
// 512 thr = 8 waves: wr = w>>1 (rows wr*64..+64), wc = w&1 (n wc*32..+32/gate).
// LDS buf 64KB: A[4 ksub][2 half][256 row][16B] @0; B[4 ksub][4 g][2 half]
// [64 n][16B] @32768. Phase p: read region p (6x b128, contiguous), stage one
// region-pair (2x gload_lds 1KB-coalesced), vmcnt(12), barrier, lgkm0, 8 MFMA.
// Stage plan: P0 -> region3 of t+1 (other buf); P1-3 -> regions 0-2 of t+2
// (current buf, just-freed). In-flight derivation: uniform vmcnt(12).
__global__ __launch_bounds__(512, 2) void lstm_gemm_kernel(
    const unsigned short* __restrict__ Ap,     // [256 kblk][8192 b][8]
    const unsigned short* __restrict__ Wt2,    // [256 kblk][4 g][1024 n][8]
    const float* __restrict__ cprev,
    float* __restrict__ out) {
  extern __shared__ char lds[];
  const int tid = threadIdx.x;
  const int l = tid & 63;
  const int w = tid >> 6;
  const int wr = w >> 1;               // 0..3
  const int wc = w & 1;                // 0..1
  const int bid = blockIdx.x;          // 512 blocks
  const int xcd = bid & 7;             // nt-slab per XCD: W-slab 2MB L2-resident
  const int cc = bid >> 3;
  const int nt = xcd * 2 + (cc >> 5);  // 16 n-tiles
  const int mt = cc & 31;              // 32 m-tiles
  const int m0 = mt << 8;
  const int n0 = nt << 6;

  char* const buf0 = lds;
  char* const buf1 = lds + 65536;

  f32x16 acc[2][4];                    // [m-frag 32rows][gate]
  #pragma unroll
  for (int mf = 0; mf < 2; ++mf)
    #pragma unroll
    for (int g = 0; g < 4; ++g) acc[mf][g] = (f32x16)0.0f;

  const int ln = l & 31;
  const int hl = l >> 5;               // k-group: k = hl*8 + e  [32x32x16 frag]

  // LDS read bases (single VGPR base + imm offsets; all reads contiguous 512B)
  const int aBase = hl * 4096 + (wr * 64 + ln) * 16;           // +p*8192 +mf*512
  const int bBase = 32768 + hl * 1024 + (wc * 32 + ln) * 16;   // +p*8192 +g*2048

  // Stage bases. A chunk c=tid: half=tid>>8, row=tid&255; kblk = t*8+j*2+half.
  const unsigned short* const gA =
      Ap + (size_t)(tid >> 8) * 65536 + (size_t)(m0 + (tid & 255)) * 8;
  // B chunk c=tid: g=tid>>7, half=(tid>>6)&1, n=tid&63.
  const unsigned short* const gB =
      Wt2 + (size_t)((tid >> 6) & 1) * 32768 +
      (size_t)((tid >> 7) * 1024 + n0 + (tid & 63)) * 8;
  const int dA = (tid & ~63) << 4;             // wave-uniform + lane*16 (HW)
  const int dB = 32768 + ((tid & ~63) << 4);

  auto stA = [&](char* buf, int j, int t) {
    load16(gA + (size_t)(t * 8 + j * 2) * 65536, buf + j * 8192 + dA);
  };
  auto stB = [&](char* buf, int j, int t) {
    load16(gB + (size_t)(t * 8 + j * 2) * 32768, buf + j * 8192 + dB);
  };

  bf16x8 aR[2], bR[4];
  auto rd = [&](const char* bufc, int p) {     // 6 ds_read_b128, conflict-free
    const char* pb = bufc + p * 8192;
    aR[0] = *(const bf16x8*)(pb + aBase);
    aR[1] = *(const bf16x8*)(pb + aBase + 512);     // +32 rows
    bR[0] = *(const bf16x8*)(pb + bBase);
    bR[1] = *(const bf16x8*)(pb + bBase + 2048);    // +1 gate
    bR[2] = *(const bf16x8*)(pb + bBase + 4096);
    bR[3] = *(const bf16x8*)(pb + bBase + 6144);
  };
  auto post = [&]() {                          // barrier -> lgkm0 -> 8 MFMA
    __builtin_amdgcn_s_barrier();
    asm volatile("s_waitcnt lgkmcnt(0)" ::: "memory");
    __builtin_amdgcn_s_setprio(1);
    #pragma unroll
    for (int mf = 0; mf < 2; ++mf)
      #pragma unroll
      for (int g = 0; g < 4; ++g)
        acc[mf][g] = __builtin_amdgcn_mfma_f32_32x32x16_bf16(
            aR[mf], bR[g], acc[mf][g], 0, 0, 0);
    __builtin_amdgcn_s_setprio(0);
    __builtin_amdgcn_s_barrier();
  };

  // Prologue: t=0 all 4 region-pairs -> buf0; t=1 regions 0-2 -> buf1
  // (region 3 of t=1 staged at t=0 P0 per plan). vmcnt(6): buf0's 8 landed.
  #pragma unroll
  for (int j = 0; j < 4; ++j) { stA(buf0, j, 0); stB(buf0, j, 0); }
  #pragma unroll
  for (int j = 0; j < 3; ++j) { stA(buf1, j, 1); stB(buf1, j, 1); }
  VMW(6);
  __builtin_amdgcn_s_barrier();

  #pragma unroll 1
  for (int t = 0; t < 30; ++t) {
    char* bufc = lds + ((t & 1) << 16);
    char* bufn = lds + (((t + 1) & 1) << 16);
    rd(bufc, 0); stA(bufn, 3, t + 1); stB(bufn, 3, t + 1); VMW(12); post();
    rd(bufc, 1); stA(bufc, 0, t + 2); stB(bufc, 0, t + 2); VMW(12); post();
    rd(bufc, 2); stA(bufc, 1, t + 2); stB(bufc, 1, t + 2); VMW(12); post();
    rd(bufc, 3); stA(bufc, 2, t + 2); stB(bufc, 2, t + 2); VMW(12); post();
  }
  // t = 30 (bufc = buf0): stages for t+2 = 32 skipped; counted tail drain.
  rd(buf0, 0); stA(buf1, 3, 31); stB(buf1, 3, 31); VMW(12); post();
  rd(buf0, 1); VMW(10); post();
  rd(buf0, 2); VMW(8);  post();
  rd(buf0, 3); VMW(6);  post();
  // t = 31 (bufc = buf1)
  rd(buf1, 0); VMW(4); post();
  rd(buf1, 1); VMW(2); post();
  rd(buf1, 2); VMW(0); post();
  rd(buf1, 3);         post();

  // Epilogue: 32x32 C/D layout col = lane&31, row = (r&3)+8*(r>>2)+4*(l>>5)
  // [m74/m101 verified]
  const int colB = n0 + wc * 32 + ln;
  #pragma unroll
  for (int mf = 0; mf < 2; ++mf) {
    #pragma unroll
    for (int r = 0; r < 16; ++r) {
      int row = m0 + wr * 64 + mf * 32 + (r & 3) + ((r >> 2) << 3) + (hl << 2);
      float gi = acc[mf][0][r];
      float gf = acc[mf][1][r];
      float go = acc[mf][2][r];
      float gu = acc[mf][3][r];
      float i_ = sigmoid_f(gi);
      float f_ = sigmoid_f(gf);
      float o_ = sigmoid_f(go);
      float u_ = tanh_f(gu);
      size_t idx = (size_t)row * 1024 + colB;
      float ct = i_ * u_ + f_ * cprev[idx];
      float ht = o_ * tanh_f(ct);
      out[idx] = ht;                   // h_t
      out[8388608 + idx] = ct;         // c_t
    }
  }
}

extern "C" void kernel_launch(void* const* d_in, const int* in_sizes, int n_in,
                              void* d_out, int out_size, void* d_ws, size_t ws_size,
                              hipStream_t stream) {
  const float* x  = (const float*)d_in[0];
  const float* h  = (const float*)d_in[1];
  const float* c  = (const float*)d_in[2];
  const float* Wx = (const float*)d_in[3];
  const float* Wh = (const float*)d_in[4];
  float* out = (float*)d_out;

  unsigned short* Ap  = (unsigned short*)d_ws;                   // 33,554,432 B
  unsigned short* Wt2 = (unsigned short*)((char*)d_ws + 33554432); // 16,777,216 B

  hipFuncSetAttribute((const void*)lstm_gemm_kernel,
                      hipFuncAttributeMaxDynamicSharedMemorySize, LDS_TOTAL);

  pack_a_kernel<<<4096, 256, 0, stream>>>(x, h, Ap);
  prep_w_kernel<<<2048, 256, 0, stream>>>(Wx, Wh, Wt2);
  lstm_gemm_kernel<<<dim3(512), dim3(512), LDS_TOTAL, stream>>>(Ap, Wt2, c, out);
}

// Round 9
// 167.483 us; speedup vs baseline: 1.4605x; 1.0062x over previous
//
#include <hip/hip_runtime.h>
#include <hip/hip_bf16.h>
#include <cstdint>

// LSTM cell: g[g,b,n] = sum_k A[b,k] * Wcat[g,k,n],  A = [x | h]  (K = 2048)
// i,f,o = sigmoid(g0,1,2), u = tanh(g3), c_t = i*u + f*c, h_t = o*tanh(c_t)
// Round 9: r8 (32x32x16, k-chunked layouts) with DOUBLED phase size:
// K=32/phase (12 ds_read + 16 MFMA + 4 gload), 64 phases total (was 128),
// uniform counted vmcnt(8) twice per K-step (was vmcnt(12) x4). Theory:
// per-phase overhead (~930cyc) is phase-count-proportional; halving phases
// amortizes it over a 2x MFMA cluster.

#define LDS_TOTAL 131072    // 2 buf x (A 32KB + B 32KB)

typedef __attribute__((ext_vector_type(8))) short bf16x8;    // 8 bf16 = 4 VGPR
typedef __attribute__((ext_vector_type(16))) float f32x16;   // 32x32 acc
typedef __attribute__((ext_vector_type(4))) unsigned int u32x4;

static __device__ __forceinline__ unsigned short f2bf(float f) {
  union { float f; unsigned int u; } v; v.f = f;
  unsigned int u = v.u;
  unsigned int r = (u + 0x7FFFu + ((u >> 16) & 1u)) >> 16;  // RTN-even
  return (unsigned short)r;
}

static __device__ __forceinline__ void load16(const void* gp, void* lp) {
  __builtin_amdgcn_global_load_lds(
      (const __attribute__((address_space(1))) void*)gp,
      (__attribute__((address_space(3))) void*)lp, 16, 0, 0);
}

static __device__ __forceinline__ float sigmoid_f(float x) {
  return 1.0f / (1.0f + __expf(-x));
}
static __device__ __forceinline__ float tanh_f(float x) {
  float e = __expf(-2.0f * fabsf(x));
  float r = (1.0f - e) / (1.0f + e);
  return copysignf(r, x);
}

// ---- prep 1: A = [x|h] -> k-chunked bf16: Ap[kblk 256][b 8192][8 elems] ----
__global__ __launch_bounds__(256) void pack_a_kernel(
    const float* __restrict__ x, const float* __restrict__ h,
    unsigned short* __restrict__ Ap) {
  __shared__ float tile[64][65];               // [b][k], pad -> no conflicts
  const int b0 = (blockIdx.x >> 5) << 6;       // 128 b-tiles
  const int k0 = (blockIdx.x & 31) << 6;       // 32 k-tiles
  const float* src; int ks;
  if (k0 < 1024) { src = x; ks = k0; } else { src = h; ks = k0 - 1024; }
  const int r = threadIdx.x >> 4;
  const int c4 = (threadIdx.x & 15) << 2;
  #pragma unroll
  for (int s = 0; s < 4; ++s) {
    float4 v = *(const float4*)(src + (size_t)(b0 + s * 16 + r) * 1024 + ks + c4);
    tile[s * 16 + r][c4 + 0] = v.x; tile[s * 16 + r][c4 + 1] = v.y;
    tile[s * 16 + r][c4 + 2] = v.z; tile[s * 16 + r][c4 + 3] = v.w;
  }
  __syncthreads();
  #pragma unroll
  for (int i = 0; i < 2; ++i) {
    int cc = i * 256 + threadIdx.x;
    int kb = cc >> 6, bb = cc & 63;
    union { unsigned short s[8]; u32x4 v; } o;
    #pragma unroll
    for (int e = 0; e < 8; ++e) o.s[e] = f2bf(tile[bb][kb * 8 + e]);
    *(u32x4*)(Ap + ((size_t)((k0 >> 3) + kb) * 8192 + b0 + bb) * 8) = o.v;
  }
}

// ---- prep 2: W -> k-chunked bf16: Wt2[kblk 256][g 4][n 1024][8 elems] ----
__global__ __launch_bounds__(256) void prep_w_kernel(
    const float* __restrict__ Wx, const float* __restrict__ Wh,
    unsigned short* __restrict__ Wt2) {
  __shared__ float tile[64][65];               // [k][n]
  const int g = blockIdx.x >> 9;               // 4 gates
  const int kt = (blockIdx.x >> 4) & 31;       // 32 k-tiles
  const int nt = blockIdx.x & 15;              // 16 n-tiles
  const int k0 = kt << 6, n0 = nt << 6;
  const float* W; int ks;
  if (k0 < 1024) { W = Wx + (size_t)g * 1048576; ks = k0; }
  else           { W = Wh + (size_t)g * 1048576; ks = k0 - 1024; }
  const int r = threadIdx.x >> 4;
  const int c4 = (threadIdx.x & 15) << 2;
  #pragma unroll
  for (int s = 0; s < 4; ++s) {
    float4 v = *(const float4*)(W + (size_t)(ks + s * 16 + r) * 1024 + n0 + c4);
    tile[s * 16 + r][c4 + 0] = v.x; tile[s * 16 + r][c4 + 1] = v.y;
    tile[s * 16 + r][c4 + 2] = v.z; tile[s * 16 + r][c4 + 3] = v.w;
  }
  __syncthreads();
  #pragma unroll
  for (int i = 0; i < 2; ++i) {
    int cc = i * 256 + threadIdx.x;
    int kb = cc >> 6, nn = cc & 63;
    union { unsigned short s[8]; u32x4 v; } o;
    #pragma unroll
    for (int e = 0; e < 8; ++e) o.s[e] = f2bf(tile[kb * 8 + e][nn]);
    *(u32x4*)(Wt2 + ((size_t)((k0 >> 3) + kb) * 4096 + g * 1024 + n0 + nn) * 8) = o.v;
  }
}

#define VMW(n) asm volatile("s_waitcnt vmcnt(" #n ")" ::: "memory")
#define LGKM0() asm volatile("s_waitcnt lgkmcnt(0)" ::: "memory")
#define BAR() __builtin_amdgcn_s_barrier()

// ---- main: fused 4-gate GEMM (32x32x16 MFMA) + LSTM epilogue ----
// 512 thr = 8 waves: wr = w>>1 (rows wr*64..+64), wc = w&1 (n wc*32..+32/gate).
// LDS buf 64KB: A[4 ksub][2 half][256 row][16B] @0; B[4 ksub][4 g][2 half]
// [64 n][16B] @32768. Phase h covers regions {2h,2h+1} (K=32): 12 ds_read +
// 4 gload_lds + vmcnt(8) + bar + lgkm0 + 16 MFMA + bar. Stage plan:
// P0(t) -> regions{2,3} of t+1 (bufn, freed @P1(t-1)); P1(t) -> regions{0,1}
// of t+2 (bufc, freed @P0(t)). Uniform vmcnt(8), tail 8/4/0.
__global__ __launch_bounds__(512, 2) void lstm_gemm_kernel(
    const unsigned short* __restrict__ Ap,     // [256 kblk][8192 b][8]
    const unsigned short* __restrict__ Wt2,    // [256 kblk][4 g][1024 n][8]
    const float* __restrict__ cprev,
    float* __restrict__ out) {
  extern __shared__ char lds[];
  const int tid = threadIdx.x;
  const int l = tid & 63;
  const int w = tid >> 6;
  const int wr = w >> 1;               // 0..3
  const int wc = w & 1;                // 0..1
  const int bid = blockIdx.x;          // 512 blocks
  const int xcd = bid & 7;             // nt-slab per XCD
  const int cc = bid >> 3;
  const int nt = xcd * 2 + (cc >> 5);  // 16 n-tiles
  const int mt = cc & 31;              // 32 m-tiles
  const int m0 = mt << 8;
  const int n0 = nt << 6;

  char* const buf0 = lds;
  char* const buf1 = lds + 65536;

  f32x16 acc[2][4];                    // [m-frag 32rows][gate]
  #pragma unroll
  for (int mf = 0; mf < 2; ++mf)
    #pragma unroll
    for (int g = 0; g < 4; ++g) acc[mf][g] = (f32x16)0.0f;

  const int ln = l & 31;
  const int hl = l >> 5;               // k-group: k = hl*8 + e  [32x32x16 frag]

  // LDS read bases (single VGPR base + imm offsets; reads contiguous 512B)
  const int aBase = hl * 4096 + (wr * 64 + ln) * 16;           // +region*8192
  const int bBase = 32768 + hl * 1024 + (wc * 32 + ln) * 16;   // +region*8192

  // Stage bases (r8-verified). A: half=tid>>8, row=tid&255; kblk=t*8+j*2+half.
  const unsigned short* const gA =
      Ap + (size_t)(tid >> 8) * 65536 + (size_t)(m0 + (tid & 255)) * 8;
  const unsigned short* const gB =
      Wt2 + (size_t)((tid >> 6) & 1) * 32768 +
      (size_t)((tid >> 7) * 1024 + n0 + (tid & 63)) * 8;
  const int dA = (tid & ~63) << 4;             // wave-uniform + lane*16 (HW)
  const int dB = 32768 + ((tid & ~63) << 4);

  auto stPair = [&](char* buf, int j, int t) {  // region j of tile t (A+B)
    load16(gA + (size_t)(t * 8 + j * 2) * 65536, buf + j * 8192 + dA);
    load16(gB + (size_t)(t * 8 + j * 2) * 32768, buf + j * 8192 + dB);
  };

  bf16x8 a_[2][2], b_[2][4];           // [region-within-phase][frag]
  auto rd2 = [&](const char* bufc, int h) {     // 12 ds_read_b128, conflict-free
    #pragma unroll
    for (int r = 0; r < 2; ++r) {
      const char* pb = bufc + (2 * h + r) * 8192;
      a_[r][0] = *(const bf16x8*)(pb + aBase);
      a_[r][1] = *(const bf16x8*)(pb + aBase + 512);     // +32 rows
      b_[r][0] = *(const bf16x8*)(pb + bBase);
      b_[r][1] = *(const bf16x8*)(pb + bBase + 2048);    // +1 gate
      b_[r][2] = *(const bf16x8*)(pb + bBase + 4096);
      b_[r][3] = *(const bf16x8*)(pb + bBase + 6144);
    }
  };
  auto mfma2 = [&]() {                          // 16 MFMA (8 chains of 2)
    __builtin_amdgcn_s_setprio(1);
    #pragma unroll
    for (int r = 0; r < 2; ++r)
      #pragma unroll
      for (int mf = 0; mf < 2; ++mf)
        #pragma unroll
        for (int g = 0; g < 4; ++g)
          acc[mf][g] = __builtin_amdgcn_mfma_f32_32x32x16_bf16(
              a_[r][mf], b_[r][g], acc[mf][g], 0, 0, 0);
    __builtin_amdgcn_s_setprio(0);
  };

  // Prologue: t=0 all 4 regions -> buf0 (8 loads); t=1 regions{0,1} -> buf1
  // (4 loads). vmcnt(4): buf0's 8 landed; buf1's may fly.
  #pragma unroll
  for (int j = 0; j < 4; ++j) stPair(buf0, j, 0);
  stPair(buf1, 0, 1); stPair(buf1, 1, 1);
  VMW(4);
  BAR();

  #pragma unroll 1
  for (int t = 0; t < 30; ++t) {
    char* bufc = lds + ((t & 1) << 16);
    char* bufn = lds + (((t + 1) & 1) << 16);
    // P0: regions {0,1}; stage t+1 regions {2,3} (bufn, freed @P1(t-1))
    rd2(bufc, 0);
    stPair(bufn, 2, t + 1); stPair(bufn, 3, t + 1);
    VMW(8); BAR(); LGKM0();
    mfma2();
    BAR();
    // P1: regions {2,3}; stage t+2 regions {0,1} (bufc, freed @P0(t))
    rd2(bufc, 1);
    stPair(bufc, 0, t + 2); stPair(bufc, 1, t + 2);
    VMW(8); BAR(); LGKM0();
    mfma2();
    BAR();
  }
  // t=30 (bufc=buf0, bufn=buf1): P1 stage (t+2=32) skipped -> tail counts.
  rd2(buf0, 0); stPair(buf1, 2, 31); stPair(buf1, 3, 31);
  VMW(8); BAR(); LGKM0(); mfma2(); BAR();
  rd2(buf0, 1);
  VMW(4); BAR(); LGKM0(); mfma2(); BAR();
  // t=31 (bufc=buf1): no stages.
  rd2(buf1, 0);
  VMW(0); BAR(); LGKM0(); mfma2(); BAR();
  rd2(buf1, 1);
  LGKM0(); mfma2();

  // Epilogue: 32x32 C/D layout col = lane&31, row = (r&3)+8*(r>>2)+4*(l>>5)
  // [m74/m101 verified]
  const int colB = n0 + wc * 32 + ln;
  #pragma unroll
  for (int mf = 0; mf < 2; ++mf) {
    #pragma unroll
    for (int r = 0; r < 16; ++r) {
      int row = m0 + wr * 64 + mf * 32 + (r & 3) + ((r >> 2) << 3) + (hl << 2);
      float gi = acc[mf][0][r];
      float gf = acc[mf][1][r];
      float go = acc[mf][2][r];
      float gu = acc[mf][3][r];
      float i_ = sigmoid_f(gi);
      float f_ = sigmoid_f(gf);
      float o_ = sigmoid_f(go);
      float u_ = tanh_f(gu);
      size_t idx = (size_t)row * 1024 + colB;
      float ct = i_ * u_ + f_ * cprev[idx];
      float ht = o_ * tanh_f(ct);
      out[idx] = ht;                   // h_t
      out[8388608 + idx] = ct;         // c_t
    }
  }
}

extern "C" void kernel_launch(void* const* d_in, const int* in_sizes, int n_in,
                              void* d_out, int out_size, void* d_ws, size_t ws_size,
                              hipStream_t stream) {
  const float* x  = (const float*)d_in[0];
  const float* h  = (const float*)d_in[1];
  const float* c  = (const float*)d_in[2];
  const float* Wx = (const float*)d_in[3];
  const float* Wh = (const float*)d_in[4];
  float* out = (float*)d_out;

  unsigned short* Ap  = (unsigned short*)d_ws;                   // 33,554,432 B
  unsigned short* Wt2 = (unsigned short*)((char*)d_ws + 33554432); // 16,777,216 B

  hipFuncSetAttribute((const void*)lstm_gemm_kernel,
                      hipFuncAttributeMaxDynamicSharedMemorySize, LDS_TOTAL);

  pack_a_kernel<<<4096, 256, 0, stream>>>(x, h, Ap);
  prep_w_kernel<<<2048, 256, 0, stream>>>(Wx, Wh, Wt2);
  lstm_gemm_kernel<<<dim3(512), dim3(512), LDS_TOTAL, stream>>>(Ap, Wt2, c, out);
}